// Round 10
// baseline (229.962 us; speedup 1.0000x reference)
//
#include <hip/hip_runtime.h>
#include <math.h>

// Problem constants
constexpr int B_ = 16;
constexpr int N_ = 2048;
constexpr int W_ = 64;
constexpr int R_ = 4;
constexpr float EPS_ = 1e-8f;

constexpr int NSTRIP = 32;           // strips per batch for link kernel
constexpr int SROWS = N_ / NSTRIP;   // 64 rows per strip
constexpr int NCHUNK = 16;           // row chunks for read_val partials

typedef float floatx4 __attribute__((ext_vector_type(4)));

// ---------------- reduction helpers ----------------
__device__ inline float warp_reduce_sum(float v) {
    for (int off = 32; off > 0; off >>= 1) v += __shfl_down(v, off);
    return v;
}
__device__ inline float warp_reduce_max(float v) {
    for (int off = 32; off > 0; off >>= 1) v = fmaxf(v, __shfl_down(v, off));
    return v;
}
__device__ inline float block_reduce_sum(float v, float* s_red, int tid, int nthreads) {
    v = warp_reduce_sum(v);
    int wv = tid >> 6, ln = tid & 63, nw = nthreads >> 6;
    if (ln == 0) s_red[wv] = v;
    __syncthreads();
    if (tid == 0) {
        float s = 0.f;
        for (int i = 0; i < nw; ++i) s += s_red[i];
        s_red[0] = s;
    }
    __syncthreads();
    float r = s_red[0];
    __syncthreads();
    return r;
}
__device__ inline float block_reduce_max(float v, float* s_red, int tid, int nthreads) {
    v = warp_reduce_max(v);
    int wv = tid >> 6, ln = tid & 63, nw = nthreads >> 6;
    if (ln == 0) s_red[wv] = v;
    __syncthreads();
    if (tid == 0) {
        float m = s_red[0];
        for (int i = 1; i < nw; ++i) m = fmaxf(m, s_red[i]);
        s_red[0] = m;
    }
    __syncthreads();
    float r = s_red[0];
    __syncthreads();
    return r;
}

// ---------------- K0: old memory row norms + write-key dots ----------------
__global__ __launch_bounds__(256) void k0_rowstats(
        const float* __restrict__ memory, const float* __restrict__ write_key,
        float* __restrict__ nsq_old, float* __restrict__ dot_wk) {
    int gwave = (blockIdx.x * blockDim.x + threadIdx.x) >> 6;
    int lane = threadIdx.x & 63;
    if (gwave >= B_ * N_) return;
    int b = gwave / N_;
    float m = memory[(size_t)gwave * W_ + lane];
    float k = write_key[b * W_ + lane];
    float nsq = warp_reduce_sum(m * m);
    float d = warp_reduce_sum(m * k);
    if (lane == 0) { nsq_old[gwave] = nsq; dot_wk[gwave] = d; }
}

// ---------------- KR: stable ascending rank of usage (replaces bitonic sort) ----------------
// grid = B*16 blocks, 128 threads; block handles 128 elements of one batch.
// Stable tie-break (value, index) matches JAX stable argsort.
__global__ __launch_bounds__(128) void kRank(
        const float* __restrict__ usage, int* __restrict__ rank) {
    int b = blockIdx.x >> 4;
    int slice = blockIdx.x & 15;
    __shared__ float s_u[N_];
    for (int i = threadIdx.x; i < N_; i += 128) s_u[i] = usage[b * N_ + i];
    __syncthreads();
    int e = slice * 128 + threadIdx.x;
    float ue = s_u[e];
    int cnt = 0;
    for (int j = 0; j < N_; j += 4) {
        floatx4 v = *(const floatx4*)&s_u[j];
        cnt += (v.x < ue) || (v.x == ue && (j + 0) < e);
        cnt += (v.y < ue) || (v.y == ue && (j + 1) < e);
        cnt += (v.z < ue) || (v.z == ue && (j + 2) < e);
        cnt += (v.w < ue) || (v.w == ue && (j + 3) < e);
    }
    rank[b * N_ + e] = cnt;
}

// ---------------- K1: per-batch write content + allocation + ww (rank-based) ----------------
__global__ __launch_bounds__(1024) void k1_ww(
        const float* __restrict__ write_key, const float* __restrict__ write_strength,
        const float* __restrict__ allocation_gate, const float* __restrict__ write_gate,
        const float* __restrict__ usage, const int* __restrict__ rank,
        const float* __restrict__ nsq_old, const float* __restrict__ dot_wk,
        float* __restrict__ o_ww, float* __restrict__ wwsum) {
    int b = blockIdx.x;
    int t = threadIdx.x;
    __shared__ float s_wc[N_];
    __shared__ float s_u[N_];
    __shared__ int   s_rank[N_];
    __shared__ float s_sorted[N_];
    __shared__ float s_excl[N_];
    __shared__ float s_scan[1024];
    __shared__ float s_red[32];

    // write-key norm (wave 0)
    if (t < 64) {
        float v = write_key[b * W_ + t];
        float sq = warp_reduce_sum(v * v);
        if (t == 0) s_red[31] = fmaxf(sqrtf(sq), EPS_);
    }
    __syncthreads();
    float knorm = s_red[31];
    float beta = write_strength[b];

    // sims + stage usage/rank; scatter usage into sorted order
    float lmax = -INFINITY;
    for (int k = 0; k < 2; ++k) {
        int n = t + k * 1024;
        float mn = fmaxf(sqrtf(nsq_old[b * N_ + n]), EPS_);
        float s = beta * dot_wk[b * N_ + n] / (knorm * mn);
        s_wc[n] = s;
        lmax = fmaxf(lmax, s);
        float u = usage[b * N_ + n];
        int rk = rank[b * N_ + n];
        s_u[n] = u;
        s_rank[n] = rk;
        s_sorted[rk] = u;
    }
    float mx = block_reduce_max(lmax, s_red, t, 1024);
    float lsum = 0.f;
    for (int k = 0; k < 2; ++k) {
        int n = t + k * 1024;
        float e = expf(s_wc[n] - mx);
        s_wc[n] = e;
        lsum += e;
    }
    float sm = block_reduce_sum(lsum, s_red, t, 1024);
    float inv = 1.f / sm;
    for (int k = 0; k < 2; ++k) {
        int n = t + k * 1024;
        s_wc[n] *= inv;   // write content weighting
    }
    __syncthreads();   // s_sorted fully scattered

    // exclusive cumprod over sorted usage (thread owns sorted elems 2t, 2t+1)
    float v0 = s_sorted[2 * t], v1 = s_sorted[2 * t + 1];
    s_scan[t] = v0 * v1;
    __syncthreads();
    for (int off = 1; off < 1024; off <<= 1) {
        float ad = (t >= off) ? s_scan[t - off] : 1.f;
        __syncthreads();
        s_scan[t] *= ad;
        __syncthreads();
    }
    float excl = (t > 0) ? s_scan[t - 1] : 1.f;
    s_excl[2 * t] = excl;
    s_excl[2 * t + 1] = excl * v0;
    __syncthreads();

    // ww = wg * (ag*(alloc - wc) + wc),  alloc[n] = (1-u[n]) * excl[rank[n]]
    float ag = allocation_gate[b], wg = write_gate[b];
    float lws = 0.f;
    for (int k = 0; k < 2; ++k) {
        int n = t + k * 1024;
        float alloc = (1.f - s_u[n]) * s_excl[s_rank[n]];
        float wc = s_wc[n];
        float wwn = wg * (ag * (alloc - wc) + wc);
        o_ww[b * N_ + n] = wwn;
        lws += wwn;
    }
    float ts = block_reduce_sum(lws, s_red, t, 1024);
    if (t == 0) wwsum[b] = ts;
}

// ---------------- K2: memory update + new row norms + read-key dots (fused k6a) ----------------
__global__ __launch_bounds__(256) void k2_memupdate(
        const float* __restrict__ memory, const float* __restrict__ erase_vector,
        const float* __restrict__ write_vector, const float* __restrict__ o_ww,
        const float* __restrict__ read_keys,
        float* __restrict__ o_mem, float* __restrict__ nsq_new,
        float* __restrict__ simsr) {
    int gwave = (blockIdx.x * blockDim.x + threadIdx.x) >> 6;
    int lane = threadIdx.x & 63;
    if (gwave >= B_ * N_) return;
    int b = gwave / N_, n = gwave % N_;
    float w = o_ww[b * N_ + n];
    float e = erase_vector[b * W_ + lane];
    float v = write_vector[b * W_ + lane];
    float m = memory[(size_t)gwave * W_ + lane];
    float nm = m * (1.f - w * e) + w * v;
    o_mem[(size_t)gwave * W_ + lane] = nm;
    float nsq = warp_reduce_sum(nm * nm);
    if (lane == 0) nsq_new[gwave] = nsq;
    for (int r = 0; r < R_; ++r) {
        float kr = read_keys[(b * R_ + r) * W_ + lane];
        float d = warp_reduce_sum(nm * kr);
        if (lane == 0) simsr[(b * R_ + r) * N_ + n] = d;
    }
}

// ---------------- K3b: precedence output (folds global ww-sum) ----------------
__global__ __launch_bounds__(256) void k3b_prec(
        const float* __restrict__ precedence, const float* __restrict__ o_ww,
        const float* __restrict__ wwsum, float* __restrict__ o_prec) {
    __shared__ float s_tot;
    if (threadIdx.x == 0) {
        float s = 0.f;
        for (int i = 0; i < B_; ++i) s += wwsum[i];
        s_tot = s;
    }
    __syncthreads();
    int i = blockIdx.x * blockDim.x + threadIdx.x;
    if (i >= B_ * N_) return;
    o_prec[i] = (1.f - s_tot) * precedence[i] + o_ww[i];
}

// ---------------- K4: link + fused fwd/bwd matvecs (barrier-free main loop) ----------------
// Block = 512 threads = 8 waves; wave w owns cols [w*256, w*256+256), lane owns 4 cols (float4).
// Each block covers SROWS rows x all 2048 cols, so fwd row-sums complete in-block.
__global__ __launch_bounds__(512) void k4_link(
        const float* __restrict__ temporal_link, const float* __restrict__ precedence,
        const float* __restrict__ read_weights, const float* __restrict__ o_ww,
        float* __restrict__ o_link, float* __restrict__ fwd, float* __restrict__ bwd_part) {
    int blk = blockIdx.x;
    int b = blk / NSTRIP;
    int strip = blk % NSTRIP;
    int t = threadIdx.x;
    int wv = t >> 6, ln = t & 63;
    int j0 = wv * 256 + ln * 4;
    int r0 = strip * SROWS;

    __shared__ float s_wwi[SROWS];
    __shared__ float s_rwi[R_][SROWS];
    __shared__ float s_part[8][SROWS][R_];

    if (t < SROWS) {
        s_wwi[t] = o_ww[b * N_ + r0 + t];
    } else if (t < SROWS * (R_ + 1)) {
        int r = t / SROWS - 1, ii = t % SROWS;
        s_rwi[r][ii] = read_weights[(b * R_ + r) * N_ + r0 + ii];
    }

    floatx4 wwj = *(const floatx4*)&o_ww[b * N_ + j0];
    floatx4 pj  = *(const floatx4*)&precedence[b * N_ + j0];
    floatx4 rwj[R_];
    for (int r = 0; r < R_; ++r)
        rwj[r] = *(const floatx4*)&read_weights[(b * R_ + r) * N_ + j0];

    floatx4 bwdloc[R_];
    for (int r = 0; r < R_; ++r) bwdloc[r] = (floatx4)(0.f);

    __syncthreads();

    for (int ii = 0; ii < SROWS; ++ii) {
        int i = r0 + ii;
        float wwi = s_wwi[ii];
        const floatx4 L = __builtin_nontemporal_load(
            (const floatx4*)&temporal_link[((size_t)b * N_ + i) * N_ + j0]);
        float base = 1.f - wwi;
        floatx4 lv;
        lv.x = (j0 + 0 == i) ? 0.f : (base - wwj.x) * L.x + wwi * pj.x;
        lv.y = (j0 + 1 == i) ? 0.f : (base - wwj.y) * L.y + wwi * pj.y;
        lv.z = (j0 + 2 == i) ? 0.f : (base - wwj.z) * L.z + wwi * pj.z;
        lv.w = (j0 + 3 == i) ? 0.f : (base - wwj.w) * L.w + wwi * pj.w;
        __builtin_nontemporal_store(lv, (floatx4*)&o_link[((size_t)b * N_ + i) * N_ + j0]);

        // fwd per-wave partial (in-wave shuffle reduce, no barrier)
        for (int r = 0; r < R_; ++r) {
            float fth = rwj[r].x * lv.x + rwj[r].y * lv.y + rwj[r].z * lv.z + rwj[r].w * lv.w;
            fth = warp_reduce_sum(fth);
            if (ln == 0) s_part[wv][ii][r] = fth;
        }
        // bwd column accumulators (registers, no cross-lane)
        for (int r = 0; r < R_; ++r) {
            float rwi = s_rwi[r][ii];
            bwdloc[r].x += rwi * lv.x;
            bwdloc[r].y += rwi * lv.y;
            bwdloc[r].z += rwi * lv.z;
            bwdloc[r].w += rwi * lv.w;
        }
    }
    __syncthreads();

    // finalize fwd for this strip's rows: sum 8 wave partials
    if (t < SROWS * R_) {
        int ii = t >> 2, r = t & 3;
        float s = 0.f;
        for (int w8 = 0; w8 < 8; ++w8) s += s_part[w8][ii][r];
        fwd[(b * R_ + r) * N_ + r0 + ii] = s;
    }

    // write bwd strip partials
    for (int r = 0; r < R_; ++r)
        *(floatx4*)&bwd_part[((size_t)blk * R_ + r) * N_ + j0] = bwdloc[r];
}

// ---------------- K6b: bwd strip-reduce + per-(b,r) softmax + rw combine ----------------
__global__ __launch_bounds__(256) void k6b_rw(
        const float* __restrict__ read_keys, const float* __restrict__ read_strength,
        const float* __restrict__ read_modes,
        const float* __restrict__ simsr, const float* __restrict__ nsq_new,
        const float* __restrict__ fwd, const float* __restrict__ bwd_part,
        float* __restrict__ o_rw) {
    int br = blockIdx.x;
    int b = br / R_, r = br % R_;
    int t = threadIdx.x;
    __shared__ float s_s[N_];
    __shared__ float s_bwd[N_];
    __shared__ float s_red[8];

    // reduce bwd partials over strips
    for (int g = 0; g < 2; ++g) {
        int j = t * 4 + g * 1024;
        floatx4 acc = (floatx4)(0.f);
        for (int st = 0; st < NSTRIP; ++st) {
            floatx4 p = *(const floatx4*)&bwd_part[((size_t)(b * NSTRIP + st) * R_ + r) * N_ + j];
            acc += p;
        }
        *(floatx4*)&s_bwd[j] = acc;
    }

    if (t < 64) {
        float v = read_keys[(b * R_ + r) * W_ + t];
        float sq = warp_reduce_sum(v * v);
        if (t == 0) s_red[7] = fmaxf(sqrtf(sq), EPS_);
    }
    __syncthreads();
    float knr = s_red[7];
    float beta = read_strength[b * R_ + r];
    float m0 = read_modes[(b * R_ + r) * 3 + 0];
    float m1 = read_modes[(b * R_ + r) * 3 + 1];
    float m2 = read_modes[(b * R_ + r) * 3 + 2];
    __syncthreads();

    float lmax = -INFINITY;
    for (int n = t; n < N_; n += 256) {
        float mn = fmaxf(sqrtf(nsq_new[b * N_ + n]), EPS_);
        float s = beta * simsr[(b * R_ + r) * N_ + n] / (knr * mn);
        s_s[n] = s;
        lmax = fmaxf(lmax, s);
    }
    float mx = block_reduce_max(lmax, s_red, t, 256);
    float lsum = 0.f;
    for (int n = t; n < N_; n += 256) {
        float e = expf(s_s[n] - mx);
        s_s[n] = e;
        lsum += e;
    }
    float sm = block_reduce_sum(lsum, s_red, t, 256);
    float inv = 1.f / sm;
    for (int n = t; n < N_; n += 256) {
        float content = s_s[n] * inv;
        float v = fwd[(b * R_ + r) * N_ + n] * m0
                + s_bwd[n] * m1
                + content * m2;
        o_rw[(b * R_ + r) * N_ + n] = v;
    }
}

// ---------------- K6c: retention + usage_new ----------------
__global__ __launch_bounds__(256) void k6c_usage(
        const float* __restrict__ free_gates, const float* __restrict__ o_rw,
        const float* __restrict__ usage, const float* __restrict__ o_ww,
        float* __restrict__ o_usage) {
    int i = blockIdx.x * blockDim.x + threadIdx.x;
    if (i >= B_ * N_) return;
    int b = i / N_, n = i % N_;
    float ret = 1.f;
    for (int r = 0; r < R_; ++r) {
        float fg = free_gates[b * R_ + r];
        float rw = o_rw[(b * R_ + r) * N_ + n];
        ret *= (1.f - fg * rw);
    }
    float u = usage[i];
    float w = o_ww[i];
    o_usage[i] = (u + w - u * w) * ret;
}

// ---------------- K6d: read_val partials ----------------
__global__ __launch_bounds__(256) void k6d_readval_part(
        const float* __restrict__ o_mem, const float* __restrict__ o_rw,
        float* __restrict__ rv_part) {
    int blk = blockIdx.x;
    int b = blk / NCHUNK;
    int chunk = blk % NCHUNK;
    int t = threadIdx.x;
    int wv = t >> 6, lane = t & 63;
    __shared__ float s_acc[4][R_][W_];

    float acc[R_];
    for (int r = 0; r < R_; ++r) acc[r] = 0.f;
    int rows_per_wave = (N_ / NCHUNK) / 4;   // 32
    int n0 = chunk * (N_ / NCHUNK) + wv * rows_per_wave;
    for (int k = 0; k < rows_per_wave; ++k) {
        int n = n0 + k;
        float m = o_mem[((size_t)b * N_ + n) * W_ + lane];
        for (int r = 0; r < R_; ++r) {
            float w = o_rw[(b * R_ + r) * N_ + n];
            acc[r] += w * m;
        }
    }
    for (int r = 0; r < R_; ++r) s_acc[wv][r][lane] = acc[r];
    __syncthreads();
    if (t < 64) {
        for (int r = 0; r < R_; ++r) {
            float s = s_acc[0][r][t] + s_acc[1][r][t] + s_acc[2][r][t] + s_acc[3][r][t];
            rv_part[((size_t)(b * NCHUNK + chunk) * R_ + r) * W_ + t] = s;
        }
    }
}

// ---------------- K6e: reduce read_val partials ----------------
__global__ __launch_bounds__(256) void k6e_readval(
        const float* __restrict__ rv_part, float* __restrict__ o_readval) {
    int o = blockIdx.x * blockDim.x + threadIdx.x;
    if (o >= B_ * R_ * W_) return;
    int b = o / (R_ * W_);
    int rw = o % (R_ * W_);
    float s = 0.f;
    for (int c = 0; c < NCHUNK; ++c)
        s += rv_part[((size_t)(b * NCHUNK + c)) * R_ * W_ + rw];
    o_readval[o] = s;
}

// ---------------- launcher ----------------
extern "C" void kernel_launch(void* const* d_in, const int* in_sizes, int n_in,
                              void* d_out, int out_size, void* d_ws, size_t ws_size,
                              hipStream_t stream) {
    const float* write_key       = (const float*)d_in[0];
    const float* write_strength  = (const float*)d_in[1];
    const float* allocation_gate = (const float*)d_in[2];
    const float* write_gate      = (const float*)d_in[3];
    const float* write_vector    = (const float*)d_in[4];
    const float* erase_vector    = (const float*)d_in[5];
    const float* read_keys       = (const float*)d_in[6];
    const float* read_strength   = (const float*)d_in[7];
    const float* read_modes      = (const float*)d_in[8];
    const float* free_gates      = (const float*)d_in[9];
    const float* memory          = (const float*)d_in[10];
    const float* usage           = (const float*)d_in[11];
    // d_in[12] write_weight: unused by the reference computation
    const float* read_weights    = (const float*)d_in[13];
    const float* temporal_link   = (const float*)d_in[14];
    const float* precedence      = (const float*)d_in[15];

    float* out = (float*)d_out;
    float* o_readval = out;                                   // B*R*W
    float* o_mem     = o_readval + B_ * R_ * W_;              // B*N*W
    float* o_ww      = o_mem + (size_t)B_ * N_ * W_;          // B*N
    float* o_rw      = o_ww + B_ * N_;                        // B*R*N
    float* o_link    = o_rw + B_ * R_ * N_;                   // B*N*N
    float* o_prec    = o_link + (size_t)B_ * N_ * N_;         // B*N
    float* o_usage   = o_prec + B_ * N_;                      // B*N

    float* ws = (float*)d_ws;
    float* w_nsq_old = ws;  ws += B_ * N_;
    float* w_dot     = ws;  ws += B_ * N_;
    float* w_nsq_new = ws;  ws += B_ * N_;
    float* w_wwsum   = ws;  ws += 64;
    int*   w_rank    = (int*)ws;  ws += B_ * N_;
    float* w_fwd     = ws;  ws += B_ * R_ * N_;
    float* w_simsr   = ws;  ws += B_ * R_ * N_;
    float* w_bwdp    = ws;  ws += (size_t)B_ * NSTRIP * R_ * N_;
    float* w_rvp     = ws;  ws += (size_t)B_ * NCHUNK * R_ * W_;

    int rows = B_ * N_;                 // 32768 rows (waves)
    int rowblocks = rows / 4;           // 4 waves per 256-thread block

    k0_rowstats<<<rowblocks, 256, 0, stream>>>(memory, write_key, w_nsq_old, w_dot);
    kRank<<<B_ * 16, 128, 0, stream>>>(usage, w_rank);
    k1_ww<<<B_, 1024, 0, stream>>>(write_key, write_strength, allocation_gate, write_gate,
                                   usage, w_rank, w_nsq_old, w_dot, o_ww, w_wwsum);
    k2_memupdate<<<rowblocks, 256, 0, stream>>>(memory, erase_vector, write_vector,
                                                o_ww, read_keys, o_mem, w_nsq_new, w_simsr);
    k3b_prec<<<(B_ * N_ + 255) / 256, 256, 0, stream>>>(precedence, o_ww, w_wwsum, o_prec);
    k4_link<<<B_ * NSTRIP, 512, 0, stream>>>(temporal_link, precedence, read_weights,
                                             o_ww, o_link, w_fwd, w_bwdp);
    k6b_rw<<<B_ * R_, 256, 0, stream>>>(read_keys, read_strength, read_modes,
                                        w_simsr, w_nsq_new, w_fwd, w_bwdp, o_rw);
    k6c_usage<<<(B_ * N_ + 255) / 256, 256, 0, stream>>>(free_gates, o_rw, usage, o_ww, o_usage);
    k6d_readval_part<<<B_ * NCHUNK, 256, 0, stream>>>(o_mem, o_rw, w_rvp);
    k6e_readval<<<(B_ * R_ * W_ + 255) / 256, 256, 0, stream>>>(w_rvp, o_readval);
}

// Round 11
// 200.749 us; speedup vs baseline: 1.1455x; 1.1455x over previous
//
#include <hip/hip_runtime.h>
#include <math.h>

// Problem constants
constexpr int B_ = 16;
constexpr int N_ = 2048;
constexpr int W_ = 64;
constexpr int R_ = 4;
constexpr float EPS_ = 1e-8f;

constexpr int NCHUNK = 16;           // row chunks for read_val partials

typedef float floatx4 __attribute__((ext_vector_type(4)));

// ---------------- reduction helpers ----------------
__device__ inline float warp_reduce_sum(float v) {
    for (int off = 32; off > 0; off >>= 1) v += __shfl_down(v, off);
    return v;
}
__device__ inline float warp_reduce_max(float v) {
    for (int off = 32; off > 0; off >>= 1) v = fmaxf(v, __shfl_down(v, off));
    return v;
}
__device__ inline float block_reduce_sum(float v, float* s_red, int tid, int nthreads) {
    v = warp_reduce_sum(v);
    int wv = tid >> 6, ln = tid & 63, nw = nthreads >> 6;
    if (ln == 0) s_red[wv] = v;
    __syncthreads();
    if (tid == 0) {
        float s = 0.f;
        for (int i = 0; i < nw; ++i) s += s_red[i];
        s_red[0] = s;
    }
    __syncthreads();
    float r = s_red[0];
    __syncthreads();
    return r;
}
__device__ inline float block_reduce_max(float v, float* s_red, int tid, int nthreads) {
    v = warp_reduce_max(v);
    int wv = tid >> 6, ln = tid & 63, nw = nthreads >> 6;
    if (ln == 0) s_red[wv] = v;
    __syncthreads();
    if (tid == 0) {
        float m = s_red[0];
        for (int i = 1; i < nw; ++i) m = fmaxf(m, s_red[i]);
        s_red[0] = m;
    }
    __syncthreads();
    float r = s_red[0];
    __syncthreads();
    return r;
}

// ---------------- K0: old memory row norms + write-key dots ----------------
__global__ __launch_bounds__(256) void k0_rowstats(
        const float* __restrict__ memory, const float* __restrict__ write_key,
        float* __restrict__ nsq_old, float* __restrict__ dot_wk) {
    int gwave = (blockIdx.x * blockDim.x + threadIdx.x) >> 6;
    int lane = threadIdx.x & 63;
    if (gwave >= B_ * N_) return;
    int b = gwave / N_;
    float m = memory[(size_t)gwave * W_ + lane];
    float k = write_key[b * W_ + lane];
    float nsq = warp_reduce_sum(m * m);
    float d = warp_reduce_sum(m * k);
    if (lane == 0) { nsq_old[gwave] = nsq; dot_wk[gwave] = d; }
}

// ---------------- K1: per-batch write content + allocation + ww ----------------
__global__ __launch_bounds__(1024) void k1_ww(
        const float* __restrict__ write_key, const float* __restrict__ write_strength,
        const float* __restrict__ allocation_gate, const float* __restrict__ write_gate,
        const float* __restrict__ usage,
        const float* __restrict__ nsq_old, const float* __restrict__ dot_wk,
        float* __restrict__ o_ww, float* __restrict__ wwsum) {
    int b = blockIdx.x;
    int t = threadIdx.x;
    __shared__ float s_wc[N_];
    __shared__ float s_vals[N_];
    __shared__ int   s_idx[N_];
    __shared__ float s_alloc[N_];
    __shared__ float s_scan[1024];
    __shared__ float s_red[32];

    // write-key norm (wave 0)
    if (t < 64) {
        float v = write_key[b * W_ + t];
        float sq = warp_reduce_sum(v * v);
        if (t == 0) s_red[31] = fmaxf(sqrtf(sq), EPS_);
    }
    __syncthreads();
    float knorm = s_red[31];
    float beta = write_strength[b];

    // sims
    float lmax = -INFINITY;
    for (int k = 0; k < 2; ++k) {
        int n = t + k * 1024;
        float mn = fmaxf(sqrtf(nsq_old[b * N_ + n]), EPS_);
        float s = beta * dot_wk[b * N_ + n] / (knorm * mn);
        s_wc[n] = s;
        lmax = fmaxf(lmax, s);
    }
    float mx = block_reduce_max(lmax, s_red, t, 1024);
    float lsum = 0.f;
    for (int k = 0; k < 2; ++k) {
        int n = t + k * 1024;
        float e = expf(s_wc[n] - mx);
        s_wc[n] = e;
        lsum += e;
    }
    float sm = block_reduce_sum(lsum, s_red, t, 1024);
    float inv = 1.f / sm;
    for (int k = 0; k < 2; ++k) {
        int n = t + k * 1024;
        s_wc[n] *= inv;   // write content weighting
    }

    // load usage for sort
    for (int k = 0; k < 2; ++k) {
        int n = t + k * 1024;
        s_vals[n] = usage[b * N_ + n];
        s_idx[n] = n;
    }
    __syncthreads();

    // bitonic sort ascending by (value, index) — matches JAX stable argsort
    for (int k = 2; k <= N_; k <<= 1) {
        for (int j = k >> 1; j > 0; j >>= 1) {
            for (int base = 0; base < 2; ++base) {
                int i = t + base * 1024;
                int ixj = i ^ j;
                if (ixj > i) {
                    bool up = ((i & k) == 0);
                    float a = s_vals[i], c = s_vals[ixj];
                    int ia = s_idx[i], ic = s_idx[ixj];
                    bool agb = (a > c) || (a == c && ia > ic);
                    if (agb == up) {
                        s_vals[i] = c; s_vals[ixj] = a;
                        s_idx[i] = ic; s_idx[ixj] = ia;
                    }
                }
            }
            __syncthreads();
        }
    }

    // exclusive cumprod scan over sorted usage (thread owns elements 2t, 2t+1)
    float v0 = s_vals[2 * t], v1 = s_vals[2 * t + 1];
    float p = v0 * v1;
    s_scan[t] = p;
    __syncthreads();
    for (int off = 1; off < 1024; off <<= 1) {
        float ad = (t >= off) ? s_scan[t - off] : 1.f;
        __syncthreads();
        s_scan[t] *= ad;
        __syncthreads();
    }
    float excl = (t > 0) ? s_scan[t - 1] : 1.f;
    float acc0 = excl;
    float acc1 = excl * v0;
    float a0 = (1.f - v0) * acc0;
    float a1 = (1.f - v1) * acc1;
    // scatter back to original positions
    s_alloc[s_idx[2 * t]] = a0;
    s_alloc[s_idx[2 * t + 1]] = a1;
    __syncthreads();

    // ww = wg * (ag*(alloc - wc) + wc)
    float ag = allocation_gate[b], wg = write_gate[b];
    float lws = 0.f;
    for (int k = 0; k < 2; ++k) {
        int n = t + k * 1024;
        float wc = s_wc[n];
        float wwn = wg * (ag * (s_alloc[n] - wc) + wc);
        o_ww[b * N_ + n] = wwn;
        lws += wwn;
    }
    float ts = block_reduce_sum(lws, s_red, t, 1024);
    if (t == 0) wwsum[b] = ts;
}

// ---------------- K2: memory update + new row norms + read-key dots (fused k6a) ----------------
__global__ __launch_bounds__(256) void k2_memupdate(
        const float* __restrict__ memory, const float* __restrict__ erase_vector,
        const float* __restrict__ write_vector, const float* __restrict__ o_ww,
        const float* __restrict__ read_keys,
        float* __restrict__ o_mem, float* __restrict__ nsq_new,
        float* __restrict__ simsr) {
    int gwave = (blockIdx.x * blockDim.x + threadIdx.x) >> 6;
    int lane = threadIdx.x & 63;
    if (gwave >= B_ * N_) return;
    int b = gwave / N_, n = gwave % N_;
    float w = o_ww[b * N_ + n];
    float e = erase_vector[b * W_ + lane];
    float v = write_vector[b * W_ + lane];
    float m = memory[(size_t)gwave * W_ + lane];
    float nm = m * (1.f - w * e) + w * v;
    o_mem[(size_t)gwave * W_ + lane] = nm;
    float nsq = warp_reduce_sum(nm * nm);
    if (lane == 0) nsq_new[gwave] = nsq;
    for (int r = 0; r < R_; ++r) {
        float kr = read_keys[(b * R_ + r) * W_ + lane];
        float d = warp_reduce_sum(nm * kr);
        if (lane == 0) simsr[(b * R_ + r) * N_ + n] = d;
    }
}

// ---------------- K3b: precedence output (folds global ww-sum) ----------------
__global__ __launch_bounds__(256) void k3b_prec(
        const float* __restrict__ precedence, const float* __restrict__ o_ww,
        const float* __restrict__ wwsum, float* __restrict__ o_prec) {
    __shared__ float s_tot;
    if (threadIdx.x == 0) {
        float s = 0.f;
        for (int i = 0; i < B_; ++i) s += wwsum[i];
        s_tot = s;
    }
    __syncthreads();
    int i = blockIdx.x * blockDim.x + threadIdx.x;
    if (i >= B_ * N_) return;
    o_prec[i] = (1.f - s_tot) * precedence[i] + o_ww[i];
}

// ---------------- K4: link + fused fwd/bwd matvecs (barrier-free main loop) ----------------
// Block = 512 threads = 8 waves; wave w owns cols [w*256, w*256+256), lane owns 4 cols (float4).
// Each block covers SR rows x all 2048 cols, so fwd row-sums complete in-block.
// NSTRIPT=64 -> grid 1024 = 4 blocks/CU (32 waves/CU) for deeper memory parallelism.
template<int NSTRIPT>
__global__ __launch_bounds__(512) void k4_link(
        const float* __restrict__ temporal_link, const float* __restrict__ precedence,
        const float* __restrict__ read_weights, const float* __restrict__ o_ww,
        float* __restrict__ o_link, float* __restrict__ fwd, float* __restrict__ bwd_part) {
    constexpr int SR = N_ / NSTRIPT;
    int blk = blockIdx.x;
    int b = blk / NSTRIPT;
    int strip = blk % NSTRIPT;
    int t = threadIdx.x;
    int wv = t >> 6, ln = t & 63;
    int j0 = wv * 256 + ln * 4;
    int r0 = strip * SR;

    __shared__ float s_wwi[SR];
    __shared__ float s_rwi[R_][SR];
    __shared__ float s_part[8][SR][R_];

    if (t < SR) {
        s_wwi[t] = o_ww[b * N_ + r0 + t];
    } else if (t < SR * (R_ + 1)) {
        int r = t / SR - 1, ii = t % SR;
        s_rwi[r][ii] = read_weights[(b * R_ + r) * N_ + r0 + ii];
    }

    floatx4 wwj = *(const floatx4*)&o_ww[b * N_ + j0];
    floatx4 pj  = *(const floatx4*)&precedence[b * N_ + j0];
    floatx4 rwj[R_];
    for (int r = 0; r < R_; ++r)
        rwj[r] = *(const floatx4*)&read_weights[(b * R_ + r) * N_ + j0];

    floatx4 bwdloc[R_];
    for (int r = 0; r < R_; ++r) bwdloc[r] = (floatx4)(0.f);

    __syncthreads();

    for (int ii = 0; ii < SR; ++ii) {
        int i = r0 + ii;
        float wwi = s_wwi[ii];
        const floatx4 L = __builtin_nontemporal_load(
            (const floatx4*)&temporal_link[((size_t)b * N_ + i) * N_ + j0]);
        float base = 1.f - wwi;
        floatx4 lv;
        lv.x = (j0 + 0 == i) ? 0.f : (base - wwj.x) * L.x + wwi * pj.x;
        lv.y = (j0 + 1 == i) ? 0.f : (base - wwj.y) * L.y + wwi * pj.y;
        lv.z = (j0 + 2 == i) ? 0.f : (base - wwj.z) * L.z + wwi * pj.z;
        lv.w = (j0 + 3 == i) ? 0.f : (base - wwj.w) * L.w + wwi * pj.w;
        __builtin_nontemporal_store(lv, (floatx4*)&o_link[((size_t)b * N_ + i) * N_ + j0]);

        // fwd per-wave partial (in-wave shuffle reduce, no barrier)
        for (int r = 0; r < R_; ++r) {
            float fth = rwj[r].x * lv.x + rwj[r].y * lv.y + rwj[r].z * lv.z + rwj[r].w * lv.w;
            fth = warp_reduce_sum(fth);
            if (ln == 0) s_part[wv][ii][r] = fth;
        }
        // bwd column accumulators (registers, no cross-lane)
        for (int r = 0; r < R_; ++r) {
            float rwi = s_rwi[r][ii];
            bwdloc[r].x += rwi * lv.x;
            bwdloc[r].y += rwi * lv.y;
            bwdloc[r].z += rwi * lv.z;
            bwdloc[r].w += rwi * lv.w;
        }
    }
    __syncthreads();

    // finalize fwd for this strip's rows: sum 8 wave partials
    if (t < SR * R_) {
        int ii = t >> 2, r = t & 3;
        float s = 0.f;
        for (int w8 = 0; w8 < 8; ++w8) s += s_part[w8][ii][r];
        fwd[(b * R_ + r) * N_ + r0 + ii] = s;
    }

    // write bwd strip partials
    for (int r = 0; r < R_; ++r)
        *(floatx4*)&bwd_part[((size_t)blk * R_ + r) * N_ + j0] = bwdloc[r];
}

// ---------------- K6b: bwd strip-reduce + per-(b,r) softmax + rw combine ----------------
template<int NSTRIPT>
__global__ __launch_bounds__(256) void k6b_rw(
        const float* __restrict__ read_keys, const float* __restrict__ read_strength,
        const float* __restrict__ read_modes,
        const float* __restrict__ simsr, const float* __restrict__ nsq_new,
        const float* __restrict__ fwd, const float* __restrict__ bwd_part,
        float* __restrict__ o_rw) {
    int br = blockIdx.x;
    int b = br / R_, r = br % R_;
    int t = threadIdx.x;
    __shared__ float s_s[N_];
    __shared__ float s_bwd[N_];
    __shared__ float s_red[8];

    // reduce bwd partials over strips
    for (int g = 0; g < 2; ++g) {
        int j = t * 4 + g * 1024;
        floatx4 acc = (floatx4)(0.f);
        for (int st = 0; st < NSTRIPT; ++st) {
            floatx4 p = *(const floatx4*)&bwd_part[((size_t)(b * NSTRIPT + st) * R_ + r) * N_ + j];
            acc += p;
        }
        *(floatx4*)&s_bwd[j] = acc;
    }

    if (t < 64) {
        float v = read_keys[(b * R_ + r) * W_ + t];
        float sq = warp_reduce_sum(v * v);
        if (t == 0) s_red[7] = fmaxf(sqrtf(sq), EPS_);
    }
    __syncthreads();
    float knr = s_red[7];
    float beta = read_strength[b * R_ + r];
    float m0 = read_modes[(b * R_ + r) * 3 + 0];
    float m1 = read_modes[(b * R_ + r) * 3 + 1];
    float m2 = read_modes[(b * R_ + r) * 3 + 2];
    __syncthreads();

    float lmax = -INFINITY;
    for (int n = t; n < N_; n += 256) {
        float mn = fmaxf(sqrtf(nsq_new[b * N_ + n]), EPS_);
        float s = beta * simsr[(b * R_ + r) * N_ + n] / (knr * mn);
        s_s[n] = s;
        lmax = fmaxf(lmax, s);
    }
    float mx = block_reduce_max(lmax, s_red, t, 256);
    float lsum = 0.f;
    for (int n = t; n < N_; n += 256) {
        float e = expf(s_s[n] - mx);
        s_s[n] = e;
        lsum += e;
    }
    float sm = block_reduce_sum(lsum, s_red, t, 256);
    float inv = 1.f / sm;
    for (int n = t; n < N_; n += 256) {
        float content = s_s[n] * inv;
        float v = fwd[(b * R_ + r) * N_ + n] * m0
                + s_bwd[n] * m1
                + content * m2;
        o_rw[(b * R_ + r) * N_ + n] = v;
    }
}

// ---------------- K6c: retention + usage_new ----------------
__global__ __launch_bounds__(256) void k6c_usage(
        const float* __restrict__ free_gates, const float* __restrict__ o_rw,
        const float* __restrict__ usage, const float* __restrict__ o_ww,
        float* __restrict__ o_usage) {
    int i = blockIdx.x * blockDim.x + threadIdx.x;
    if (i >= B_ * N_) return;
    int b = i / N_, n = i % N_;
    float ret = 1.f;
    for (int r = 0; r < R_; ++r) {
        float fg = free_gates[b * R_ + r];
        float rw = o_rw[(b * R_ + r) * N_ + n];
        ret *= (1.f - fg * rw);
    }
    float u = usage[i];
    float w = o_ww[i];
    o_usage[i] = (u + w - u * w) * ret;
}

// ---------------- K6d: read_val partials ----------------
__global__ __launch_bounds__(256) void k6d_readval_part(
        const float* __restrict__ o_mem, const float* __restrict__ o_rw,
        float* __restrict__ rv_part) {
    int blk = blockIdx.x;
    int b = blk / NCHUNK;
    int chunk = blk % NCHUNK;
    int t = threadIdx.x;
    int wv = t >> 6, lane = t & 63;
    __shared__ float s_acc[4][R_][W_];

    float acc[R_];
    for (int r = 0; r < R_; ++r) acc[r] = 0.f;
    int rows_per_wave = (N_ / NCHUNK) / 4;   // 32
    int n0 = chunk * (N_ / NCHUNK) + wv * rows_per_wave;
    for (int k = 0; k < rows_per_wave; ++k) {
        int n = n0 + k;
        float m = o_mem[((size_t)b * N_ + n) * W_ + lane];
        for (int r = 0; r < R_; ++r) {
            float w = o_rw[(b * R_ + r) * N_ + n];
            acc[r] += w * m;
        }
    }
    for (int r = 0; r < R_; ++r) s_acc[wv][r][lane] = acc[r];
    __syncthreads();
    if (t < 64) {
        for (int r = 0; r < R_; ++r) {
            float s = s_acc[0][r][t] + s_acc[1][r][t] + s_acc[2][r][t] + s_acc[3][r][t];
            rv_part[((size_t)(b * NCHUNK + chunk) * R_ + r) * W_ + t] = s;
        }
    }
}

// ---------------- K6e: reduce read_val partials ----------------
__global__ __launch_bounds__(256) void k6e_readval(
        const float* __restrict__ rv_part, float* __restrict__ o_readval) {
    int o = blockIdx.x * blockDim.x + threadIdx.x;
    if (o >= B_ * R_ * W_) return;
    int b = o / (R_ * W_);
    int rw = o % (R_ * W_);
    float s = 0.f;
    for (int c = 0; c < NCHUNK; ++c)
        s += rv_part[((size_t)(b * NCHUNK + c)) * R_ * W_ + rw];
    o_readval[o] = s;
}

// ---------------- launcher ----------------
extern "C" void kernel_launch(void* const* d_in, const int* in_sizes, int n_in,
                              void* d_out, int out_size, void* d_ws, size_t ws_size,
                              hipStream_t stream) {
    const float* write_key       = (const float*)d_in[0];
    const float* write_strength  = (const float*)d_in[1];
    const float* allocation_gate = (const float*)d_in[2];
    const float* write_gate      = (const float*)d_in[3];
    const float* write_vector    = (const float*)d_in[4];
    const float* erase_vector    = (const float*)d_in[5];
    const float* read_keys       = (const float*)d_in[6];
    const float* read_strength   = (const float*)d_in[7];
    const float* read_modes      = (const float*)d_in[8];
    const float* free_gates      = (const float*)d_in[9];
    const float* memory          = (const float*)d_in[10];
    const float* usage           = (const float*)d_in[11];
    // d_in[12] write_weight: unused by the reference computation
    const float* read_weights    = (const float*)d_in[13];
    const float* temporal_link   = (const float*)d_in[14];
    const float* precedence      = (const float*)d_in[15];

    float* out = (float*)d_out;
    float* o_readval = out;                                   // B*R*W
    float* o_mem     = o_readval + B_ * R_ * W_;              // B*N*W
    float* o_ww      = o_mem + (size_t)B_ * N_ * W_;          // B*N
    float* o_rw      = o_ww + B_ * N_;                        // B*R*N
    float* o_link    = o_rw + B_ * R_ * N_;                   // B*N*N
    float* o_prec    = o_link + (size_t)B_ * N_ * N_;         // B*N
    float* o_usage   = o_prec + B_ * N_;                      // B*N

    float* ws = (float*)d_ws;
    float* w_nsq_old = ws;  ws += B_ * N_;
    float* w_dot     = ws;  ws += B_ * N_;
    float* w_nsq_new = ws;  ws += B_ * N_;
    float* w_wwsum   = ws;  ws += 64;
    float* w_fwd     = ws;  ws += B_ * R_ * N_;
    float* w_simsr   = ws;  ws += B_ * R_ * N_;
    float* w_rvp     = ws;  ws += (size_t)B_ * NCHUNK * R_ * W_;
    float* w_bwdp    = ws;   // variable size: B * NSTRIP * R * N

    // choose NSTRIP by available workspace (deterministic: ws_size is fixed)
    size_t fixed_bytes = (size_t)((char*)w_bwdp - (char*)d_ws);
    size_t need64 = fixed_bytes + (size_t)B_ * 64 * R_ * N_ * sizeof(float);
    bool big = (ws_size >= need64);

    int rows = B_ * N_;                 // 32768 rows (waves)
    int rowblocks = rows / 4;           // 4 waves per 256-thread block

    k0_rowstats<<<rowblocks, 256, 0, stream>>>(memory, write_key, w_nsq_old, w_dot);
    k1_ww<<<B_, 1024, 0, stream>>>(write_key, write_strength, allocation_gate, write_gate,
                                   usage, w_nsq_old, w_dot, o_ww, w_wwsum);
    k2_memupdate<<<rowblocks, 256, 0, stream>>>(memory, erase_vector, write_vector,
                                                o_ww, read_keys, o_mem, w_nsq_new, w_simsr);
    k3b_prec<<<(B_ * N_ + 255) / 256, 256, 0, stream>>>(precedence, o_ww, w_wwsum, o_prec);
    if (big) {
        k4_link<64><<<B_ * 64, 512, 0, stream>>>(temporal_link, precedence, read_weights,
                                                 o_ww, o_link, w_fwd, w_bwdp);
        k6b_rw<64><<<B_ * R_, 256, 0, stream>>>(read_keys, read_strength, read_modes,
                                                w_simsr, w_nsq_new, w_fwd, w_bwdp, o_rw);
    } else {
        k4_link<32><<<B_ * 32, 512, 0, stream>>>(temporal_link, precedence, read_weights,
                                                 o_ww, o_link, w_fwd, w_bwdp);
        k6b_rw<32><<<B_ * R_, 256, 0, stream>>>(read_keys, read_strength, read_modes,
                                                w_simsr, w_nsq_new, w_fwd, w_bwdp, o_rw);
    }
    k6c_usage<<<(B_ * N_ + 255) / 256, 256, 0, stream>>>(free_gates, o_rw, usage, o_ww, o_usage);
    k6d_readval_part<<<B_ * NCHUNK, 256, 0, stream>>>(o_mem, o_rw, w_rvp);
    k6e_readval<<<(B_ * R_ * W_ + 255) / 256, 256, 0, stream>>>(w_rvp, o_readval);
}

// Round 13
// 199.584 us; speedup vs baseline: 1.1522x; 1.0058x over previous
//
#include <hip/hip_runtime.h>
#include <math.h>

// Problem constants
constexpr int B_ = 16;
constexpr int N_ = 2048;
constexpr int W_ = 64;
constexpr int R_ = 4;
constexpr float EPS_ = 1e-8f;

constexpr int NCHUNK = 16;           // row chunks for read_val partials

typedef float floatx4 __attribute__((ext_vector_type(4)));

// ---------------- reduction helpers ----------------
__device__ inline float warp_reduce_sum(float v) {
    for (int off = 32; off > 0; off >>= 1) v += __shfl_down(v, off);
    return v;
}
__device__ inline float warp_reduce_max(float v) {
    for (int off = 32; off > 0; off >>= 1) v = fmaxf(v, __shfl_down(v, off));
    return v;
}
__device__ inline float block_reduce_sum(float v, float* s_red, int tid, int nthreads) {
    v = warp_reduce_sum(v);
    int wv = tid >> 6, ln = tid & 63, nw = nthreads >> 6;
    if (ln == 0) s_red[wv] = v;
    __syncthreads();
    if (tid == 0) {
        float s = 0.f;
        for (int i = 0; i < nw; ++i) s += s_red[i];
        s_red[0] = s;
    }
    __syncthreads();
    float r = s_red[0];
    __syncthreads();
    return r;
}
__device__ inline float block_reduce_max(float v, float* s_red, int tid, int nthreads) {
    v = warp_reduce_max(v);
    int wv = tid >> 6, ln = tid & 63, nw = nthreads >> 6;
    if (ln == 0) s_red[wv] = v;
    __syncthreads();
    if (tid == 0) {
        float m = s_red[0];
        for (int i = 1; i < nw; ++i) m = fmaxf(m, s_red[i]);
        s_red[0] = m;
    }
    __syncthreads();
    float r = s_red[0];
    __syncthreads();
    return r;
}

// ---------------- K0: old memory row norms + write-key dots ----------------
__global__ __launch_bounds__(256) void k0_rowstats(
        const float* __restrict__ memory, const float* __restrict__ write_key,
        float* __restrict__ nsq_old, float* __restrict__ dot_wk) {
    int gwave = (blockIdx.x * blockDim.x + threadIdx.x) >> 6;
    int lane = threadIdx.x & 63;
    if (gwave >= B_ * N_) return;
    int b = gwave / N_;
    float m = memory[(size_t)gwave * W_ + lane];
    float k = write_key[b * W_ + lane];
    float nsq = warp_reduce_sum(m * m);
    float d = warp_reduce_sum(m * k);
    if (lane == 0) { nsq_old[gwave] = nsq; dot_wk[gwave] = d; }
}

// ---------------- K1: per-batch write content + allocation + ww ----------------
__global__ __launch_bounds__(1024) void k1_ww(
        const float* __restrict__ write_key, const float* __restrict__ write_strength,
        const float* __restrict__ allocation_gate, const float* __restrict__ write_gate,
        const float* __restrict__ usage,
        const float* __restrict__ nsq_old, const float* __restrict__ dot_wk,
        float* __restrict__ o_ww, float* __restrict__ wwsum) {
    int b = blockIdx.x;
    int t = threadIdx.x;
    __shared__ float s_wc[N_];
    __shared__ float s_vals[N_];
    __shared__ int   s_idx[N_];
    __shared__ float s_alloc[N_];
    __shared__ float s_scan[1024];
    __shared__ float s_red[32];

    // write-key norm (wave 0)
    if (t < 64) {
        float v = write_key[b * W_ + t];
        float sq = warp_reduce_sum(v * v);
        if (t == 0) s_red[31] = fmaxf(sqrtf(sq), EPS_);
    }
    __syncthreads();
    float knorm = s_red[31];
    float beta = write_strength[b];

    // sims
    float lmax = -INFINITY;
    for (int k = 0; k < 2; ++k) {
        int n = t + k * 1024;
        float mn = fmaxf(sqrtf(nsq_old[b * N_ + n]), EPS_);
        float s = beta * dot_wk[b * N_ + n] / (knorm * mn);
        s_wc[n] = s;
        lmax = fmaxf(lmax, s);
    }
    float mx = block_reduce_max(lmax, s_red, t, 1024);
    float lsum = 0.f;
    for (int k = 0; k < 2; ++k) {
        int n = t + k * 1024;
        float e = expf(s_wc[n] - mx);
        s_wc[n] = e;
        lsum += e;
    }
    float sm = block_reduce_sum(lsum, s_red, t, 1024);
    float inv = 1.f / sm;
    for (int k = 0; k < 2; ++k) {
        int n = t + k * 1024;
        s_wc[n] *= inv;   // write content weighting
    }

    // load usage for sort
    for (int k = 0; k < 2; ++k) {
        int n = t + k * 1024;
        s_vals[n] = usage[b * N_ + n];
        s_idx[n] = n;
    }
    __syncthreads();

    // bitonic sort ascending by (value, index) — matches JAX stable argsort
    for (int k = 2; k <= N_; k <<= 1) {
        for (int j = k >> 1; j > 0; j >>= 1) {
            for (int base = 0; base < 2; ++base) {
                int i = t + base * 1024;
                int ixj = i ^ j;
                if (ixj > i) {
                    bool up = ((i & k) == 0);
                    float a = s_vals[i], c = s_vals[ixj];
                    int ia = s_idx[i], ic = s_idx[ixj];
                    bool agb = (a > c) || (a == c && ia > ic);
                    if (agb == up) {
                        s_vals[i] = c; s_vals[ixj] = a;
                        s_idx[i] = ic; s_idx[ixj] = ia;
                    }
                }
            }
            __syncthreads();
        }
    }

    // exclusive cumprod scan over sorted usage (thread owns elements 2t, 2t+1)
    float v0 = s_vals[2 * t], v1 = s_vals[2 * t + 1];
    float p = v0 * v1;
    s_scan[t] = p;
    __syncthreads();
    for (int off = 1; off < 1024; off <<= 1) {
        float ad = (t >= off) ? s_scan[t - off] : 1.f;
        __syncthreads();
        s_scan[t] *= ad;
        __syncthreads();
    }
    float excl = (t > 0) ? s_scan[t - 1] : 1.f;
    float acc0 = excl;
    float acc1 = excl * v0;
    float a0 = (1.f - v0) * acc0;
    float a1 = (1.f - v1) * acc1;
    // scatter back to original positions
    s_alloc[s_idx[2 * t]] = a0;
    s_alloc[s_idx[2 * t + 1]] = a1;
    __syncthreads();

    // ww = wg * (ag*(alloc - wc) + wc)
    float ag = allocation_gate[b], wg = write_gate[b];
    float lws = 0.f;
    for (int k = 0; k < 2; ++k) {
        int n = t + k * 1024;
        float wc = s_wc[n];
        float wwn = wg * (ag * (s_alloc[n] - wc) + wc);
        o_ww[b * N_ + n] = wwn;
        lws += wwn;
    }
    float ts = block_reduce_sum(lws, s_red, t, 1024);
    if (t == 0) wwsum[b] = ts;
}

// ---------------- K2: memory update + new row norms + read-key dots (fused k6a) ----------------
__global__ __launch_bounds__(256) void k2_memupdate(
        const float* __restrict__ memory, const float* __restrict__ erase_vector,
        const float* __restrict__ write_vector, const float* __restrict__ o_ww,
        const float* __restrict__ read_keys,
        float* __restrict__ o_mem, float* __restrict__ nsq_new,
        float* __restrict__ simsr) {
    int gwave = (blockIdx.x * blockDim.x + threadIdx.x) >> 6;
    int lane = threadIdx.x & 63;
    if (gwave >= B_ * N_) return;
    int b = gwave / N_, n = gwave % N_;
    float w = o_ww[b * N_ + n];
    float e = erase_vector[b * W_ + lane];
    float v = write_vector[b * W_ + lane];
    float m = memory[(size_t)gwave * W_ + lane];
    float nm = m * (1.f - w * e) + w * v;
    o_mem[(size_t)gwave * W_ + lane] = nm;
    float nsq = warp_reduce_sum(nm * nm);
    if (lane == 0) nsq_new[gwave] = nsq;
    for (int r = 0; r < R_; ++r) {
        float kr = read_keys[(b * R_ + r) * W_ + lane];
        float d = warp_reduce_sum(nm * kr);
        if (lane == 0) simsr[(b * R_ + r) * N_ + n] = d;
    }
}

// ---------------- K3b: precedence output (folds global ww-sum) ----------------
__global__ __launch_bounds__(256) void k3b_prec(
        const float* __restrict__ precedence, const float* __restrict__ o_ww,
        const float* __restrict__ wwsum, float* __restrict__ o_prec) {
    __shared__ float s_tot;
    if (threadIdx.x == 0) {
        float s = 0.f;
        for (int i = 0; i < B_; ++i) s += wwsum[i];
        s_tot = s;
    }
    __syncthreads();
    int i = blockIdx.x * blockDim.x + threadIdx.x;
    if (i >= B_ * N_) return;
    o_prec[i] = (1.f - s_tot) * precedence[i] + o_ww[i];
}

// ---------------- K4: link + fused fwd/bwd matvecs (barrier-free main loop) ----------------
// Block = 512 threads = 8 waves; wave w owns cols [w*256, w*256+256), lane owns 4 cols (float4).
// Each block covers SR rows x all 2048 cols, so fwd row-sums complete in-block.
// NSTRIPT=64 -> grid 1024 = 4 blocks/CU (32 waves/CU) for deeper memory parallelism.
template<int NSTRIPT>
__global__ __launch_bounds__(512) void k4_link(
        const float* __restrict__ temporal_link, const float* __restrict__ precedence,
        const float* __restrict__ read_weights, const float* __restrict__ o_ww,
        float* __restrict__ o_link, float* __restrict__ fwd, float* __restrict__ bwd_part) {
    constexpr int SR = N_ / NSTRIPT;
    int blk = blockIdx.x;
    int b = blk / NSTRIPT;
    int strip = blk % NSTRIPT;
    int t = threadIdx.x;
    int wv = t >> 6, ln = t & 63;
    int j0 = wv * 256 + ln * 4;
    int r0 = strip * SR;

    __shared__ float s_wwi[SR];
    __shared__ float s_rwi[R_][SR];
    __shared__ float s_part[8][SR][R_];

    if (t < SR) {
        s_wwi[t] = o_ww[b * N_ + r0 + t];
    } else if (t < SR * (R_ + 1)) {
        int r = t / SR - 1, ii = t % SR;
        s_rwi[r][ii] = read_weights[(b * R_ + r) * N_ + r0 + ii];
    }

    floatx4 wwj = *(const floatx4*)&o_ww[b * N_ + j0];
    floatx4 pj  = *(const floatx4*)&precedence[b * N_ + j0];
    floatx4 rwj[R_];
    for (int r = 0; r < R_; ++r)
        rwj[r] = *(const floatx4*)&read_weights[(b * R_ + r) * N_ + j0];

    floatx4 bwdloc[R_];
    for (int r = 0; r < R_; ++r) bwdloc[r] = (floatx4)(0.f);

    __syncthreads();

    for (int ii = 0; ii < SR; ++ii) {
        int i = r0 + ii;
        float wwi = s_wwi[ii];
        const floatx4 L = __builtin_nontemporal_load(
            (const floatx4*)&temporal_link[((size_t)b * N_ + i) * N_ + j0]);
        float base = 1.f - wwi;
        floatx4 lv;
        lv.x = (j0 + 0 == i) ? 0.f : (base - wwj.x) * L.x + wwi * pj.x;
        lv.y = (j0 + 1 == i) ? 0.f : (base - wwj.y) * L.y + wwi * pj.y;
        lv.z = (j0 + 2 == i) ? 0.f : (base - wwj.z) * L.z + wwi * pj.z;
        lv.w = (j0 + 3 == i) ? 0.f : (base - wwj.w) * L.w + wwi * pj.w;
        __builtin_nontemporal_store(lv, (floatx4*)&o_link[((size_t)b * N_ + i) * N_ + j0]);

        // fwd per-wave partial (in-wave shuffle reduce, no barrier)
        for (int r = 0; r < R_; ++r) {
            float fth = rwj[r].x * lv.x + rwj[r].y * lv.y + rwj[r].z * lv.z + rwj[r].w * lv.w;
            fth = warp_reduce_sum(fth);
            if (ln == 0) s_part[wv][ii][r] = fth;
        }
        // bwd column accumulators (registers, no cross-lane)
        for (int r = 0; r < R_; ++r) {
            float rwi = s_rwi[r][ii];
            bwdloc[r].x += rwi * lv.x;
            bwdloc[r].y += rwi * lv.y;
            bwdloc[r].z += rwi * lv.z;
            bwdloc[r].w += rwi * lv.w;
        }
    }
    __syncthreads();

    // finalize fwd for this strip's rows: sum 8 wave partials
    if (t < SR * R_) {
        int ii = t >> 2, r = t & 3;
        float s = 0.f;
        for (int w8 = 0; w8 < 8; ++w8) s += s_part[w8][ii][r];
        fwd[(b * R_ + r) * N_ + r0 + ii] = s;
    }

    // write bwd strip partials
    for (int r = 0; r < R_; ++r)
        *(floatx4*)&bwd_part[((size_t)blk * R_ + r) * N_ + j0] = bwdloc[r];
}

// ---------------- K5: full-GPU bwd strip-reduce ----------------
// grid = B*R*N/4/256 = 128 blocks; each thread owns one float4 position,
// loops NSTRIPT independent strided loads (pipelines fully).
template<int NSTRIPT>
__global__ __launch_bounds__(256) void k5_bwdreduce(
        const float* __restrict__ bwd_part, float* __restrict__ bwd) {
    int o = blockIdx.x * 256 + threadIdx.x;            // float4 index
    constexpr int Q = R_ * N_ / 4;                     // float4s per (b,strip)
    int b = o / Q;
    int rn = o % Q;
    floatx4 acc = (floatx4)(0.f);
    const floatx4* src = (const floatx4*)bwd_part;
    for (int st = 0; st < NSTRIPT; ++st)
        acc += src[((size_t)(b * NSTRIPT + st)) * Q + rn];
    ((floatx4*)bwd)[o] = acc;
}

// ---------------- K6b: per-(b,r) softmax + rw combine (reads final bwd) ----------------
__global__ __launch_bounds__(256) void k6b_rw(
        const float* __restrict__ read_keys, const float* __restrict__ read_strength,
        const float* __restrict__ read_modes,
        const float* __restrict__ simsr, const float* __restrict__ nsq_new,
        const float* __restrict__ fwd, const float* __restrict__ bwd,
        float* __restrict__ o_rw) {
    int br = blockIdx.x;
    int b = br / R_, r = br % R_;
    int t = threadIdx.x;
    __shared__ float s_s[N_];
    __shared__ float s_red[8];

    if (t < 64) {
        float v = read_keys[(b * R_ + r) * W_ + t];
        float sq = warp_reduce_sum(v * v);
        if (t == 0) s_red[7] = fmaxf(sqrtf(sq), EPS_);
    }
    __syncthreads();
    float knr = s_red[7];
    float beta = read_strength[b * R_ + r];
    float m0 = read_modes[(b * R_ + r) * 3 + 0];
    float m1 = read_modes[(b * R_ + r) * 3 + 1];
    float m2 = read_modes[(b * R_ + r) * 3 + 2];
    __syncthreads();

    float lmax = -INFINITY;
    for (int n = t; n < N_; n += 256) {
        float mn = fmaxf(sqrtf(nsq_new[b * N_ + n]), EPS_);
        float s = beta * simsr[(b * R_ + r) * N_ + n] / (knr * mn);
        s_s[n] = s;
        lmax = fmaxf(lmax, s);
    }
    float mx = block_reduce_max(lmax, s_red, t, 256);
    float lsum = 0.f;
    for (int n = t; n < N_; n += 256) {
        float e = expf(s_s[n] - mx);
        s_s[n] = e;
        lsum += e;
    }
    float sm = block_reduce_sum(lsum, s_red, t, 256);
    float inv = 1.f / sm;
    for (int n = t; n < N_; n += 256) {
        float content = s_s[n] * inv;
        float v = fwd[(b * R_ + r) * N_ + n] * m0
                + bwd[(b * R_ + r) * N_ + n] * m1
                + content * m2;
        o_rw[(b * R_ + r) * N_ + n] = v;
    }
}

// ---------------- K6c: retention + usage_new ----------------
__global__ __launch_bounds__(256) void k6c_usage(
        const float* __restrict__ free_gates, const float* __restrict__ o_rw,
        const float* __restrict__ usage, const float* __restrict__ o_ww,
        float* __restrict__ o_usage) {
    int i = blockIdx.x * blockDim.x + threadIdx.x;
    if (i >= B_ * N_) return;
    int b = i / N_, n = i % N_;
    float ret = 1.f;
    for (int r = 0; r < R_; ++r) {
        float fg = free_gates[b * R_ + r];
        float rw = o_rw[(b * R_ + r) * N_ + n];
        ret *= (1.f - fg * rw);
    }
    float u = usage[i];
    float w = o_ww[i];
    o_usage[i] = (u + w - u * w) * ret;
}

// ---------------- K6d: read_val partials ----------------
__global__ __launch_bounds__(256) void k6d_readval_part(
        const float* __restrict__ o_mem, const float* __restrict__ o_rw,
        float* __restrict__ rv_part) {
    int blk = blockIdx.x;
    int b = blk / NCHUNK;
    int chunk = blk % NCHUNK;
    int t = threadIdx.x;
    int wv = t >> 6, lane = t & 63;
    __shared__ float s_acc[4][R_][W_];

    float acc[R_];
    for (int r = 0; r < R_; ++r) acc[r] = 0.f;
    int rows_per_wave = (N_ / NCHUNK) / 4;   // 32
    int n0 = chunk * (N_ / NCHUNK) + wv * rows_per_wave;
    for (int k = 0; k < rows_per_wave; ++k) {
        int n = n0 + k;
        float m = o_mem[((size_t)b * N_ + n) * W_ + lane];
        for (int r = 0; r < R_; ++r) {
            float w = o_rw[(b * R_ + r) * N_ + n];
            acc[r] += w * m;
        }
    }
    for (int r = 0; r < R_; ++r) s_acc[wv][r][lane] = acc[r];
    __syncthreads();
    if (t < 64) {
        for (int r = 0; r < R_; ++r) {
            float s = s_acc[0][r][t] + s_acc[1][r][t] + s_acc[2][r][t] + s_acc[3][r][t];
            rv_part[((size_t)(b * NCHUNK + chunk) * R_ + r) * W_ + t] = s;
        }
    }
}

// ---------------- K6e: reduce read_val partials ----------------
__global__ __launch_bounds__(256) void k6e_readval(
        const float* __restrict__ rv_part, float* __restrict__ o_readval) {
    int o = blockIdx.x * blockDim.x + threadIdx.x;
    if (o >= B_ * R_ * W_) return;
    int b = o / (R_ * W_);
    int rw = o % (R_ * W_);
    float s = 0.f;
    for (int c = 0; c < NCHUNK; ++c)
        s += rv_part[((size_t)(b * NCHUNK + c)) * R_ * W_ + rw];
    o_readval[o] = s;
}

// ---------------- launcher ----------------
extern "C" void kernel_launch(void* const* d_in, const int* in_sizes, int n_in,
                              void* d_out, int out_size, void* d_ws, size_t ws_size,
                              hipStream_t stream) {
    const float* write_key       = (const float*)d_in[0];
    const float* write_strength  = (const float*)d_in[1];
    const float* allocation_gate = (const float*)d_in[2];
    const float* write_gate      = (const float*)d_in[3];
    const float* write_vector    = (const float*)d_in[4];
    const float* erase_vector    = (const float*)d_in[5];
    const float* read_keys       = (const float*)d_in[6];
    const float* read_strength   = (const float*)d_in[7];
    const float* read_modes      = (const float*)d_in[8];
    const float* free_gates      = (const float*)d_in[9];
    const float* memory          = (const float*)d_in[10];
    const float* usage           = (const float*)d_in[11];
    // d_in[12] write_weight: unused by the reference computation
    const float* read_weights    = (const float*)d_in[13];
    const float* temporal_link   = (const float*)d_in[14];
    const float* precedence      = (const float*)d_in[15];

    float* out = (float*)d_out;
    float* o_readval = out;                                   // B*R*W
    float* o_mem     = o_readval + B_ * R_ * W_;              // B*N*W
    float* o_ww      = o_mem + (size_t)B_ * N_ * W_;          // B*N
    float* o_rw      = o_ww + B_ * N_;                        // B*R*N
    float* o_link    = o_rw + B_ * R_ * N_;                   // B*N*N
    float* o_prec    = o_link + (size_t)B_ * N_ * N_;         // B*N
    float* o_usage   = o_prec + B_ * N_;                      // B*N

    float* ws = (float*)d_ws;
    float* w_nsq_old = ws;  ws += B_ * N_;
    float* w_dot     = ws;  ws += B_ * N_;
    float* w_nsq_new = ws;  ws += B_ * N_;
    float* w_wwsum   = ws;  ws += 64;
    float* w_fwd     = ws;  ws += B_ * R_ * N_;
    float* w_bwd     = ws;  ws += B_ * R_ * N_;
    float* w_simsr   = ws;  ws += B_ * R_ * N_;
    float* w_rvp     = ws;  ws += (size_t)B_ * NCHUNK * R_ * W_;
    float* w_bwdp    = ws;   // variable size: B * NSTRIP * R * N

    // choose NSTRIP by available workspace (deterministic: ws_size is fixed)
    size_t fixed_bytes = (size_t)((char*)w_bwdp - (char*)d_ws);
    size_t need64 = fixed_bytes + (size_t)B_ * 64 * R_ * N_ * sizeof(float);
    bool big = (ws_size >= need64);

    int rows = B_ * N_;                 // 32768 rows (waves)
    int rowblocks = rows / 4;           // 4 waves per 256-thread block
    int redblocks = B_ * R_ * N_ / 4 / 256;   // 128 blocks for k5

    k0_rowstats<<<rowblocks, 256, 0, stream>>>(memory, write_key, w_nsq_old, w_dot);
    k1_ww<<<B_, 1024, 0, stream>>>(write_key, write_strength, allocation_gate, write_gate,
                                   usage, w_nsq_old, w_dot, o_ww, w_wwsum);
    k2_memupdate<<<rowblocks, 256, 0, stream>>>(memory, erase_vector, write_vector,
                                                o_ww, read_keys, o_mem, w_nsq_new, w_simsr);
    k3b_prec<<<(B_ * N_ + 255) / 256, 256, 0, stream>>>(precedence, o_ww, w_wwsum, o_prec);
    if (big) {
        k4_link<64><<<B_ * 64, 512, 0, stream>>>(temporal_link, precedence, read_weights,
                                                 o_ww, o_link, w_fwd, w_bwdp);
        k5_bwdreduce<64><<<redblocks, 256, 0, stream>>>(w_bwdp, w_bwd);
    } else {
        k4_link<32><<<B_ * 32, 512, 0, stream>>>(temporal_link, precedence, read_weights,
                                                 o_ww, o_link, w_fwd, w_bwdp);
        k5_bwdreduce<32><<<redblocks, 256, 0, stream>>>(w_bwdp, w_bwd);
    }
    k6b_rw<<<B_ * R_, 256, 0, stream>>>(read_keys, read_strength, read_modes,
                                        w_simsr, w_nsq_new, w_fwd, w_bwd, o_rw);
    k6c_usage<<<(B_ * N_ + 255) / 256, 256, 0, stream>>>(free_gates, o_rw, usage, o_ww, o_usage);
    k6d_readval_part<<<B_ * NCHUNK, 256, 0, stream>>>(o_mem, o_rw, w_rvp);
    k6e_readval<<<(B_ * R_ * W_ + 255) / 256, 256, 0, stream>>>(w_rvp, o_readval);
}